// Round 8
// baseline (151.789 us; speedup 1.0000x reference)
//
#include <hip/hip_runtime.h>
#include <hip/hip_bf16.h>
#include <cmath>

#define BATCH 4
#define TLEN  4096
#define CEMB  1024
#define HEAD  64
#define NROWS (BATCH * TLEN)          // 16384 token rows

typedef __bf16 bf16;
typedef __attribute__((ext_vector_type(8))) __bf16 bf16x8;
typedef __attribute__((ext_vector_type(4))) __bf16 bf16x4;
typedef __attribute__((ext_vector_type(4))) float f32x4;
typedef __attribute__((ext_vector_type(16))) float f32x16;
typedef __attribute__((ext_vector_type(4))) unsigned u32x4;

#define QSCALE 0.1803368801111204f    // (1/sqrt(64)) * log2(e)

static __device__ __forceinline__ f32x4 mfma16(bf16x8 a, bf16x8 b, f32x4 c) {
    return __builtin_amdgcn_mfma_f32_16x16x32_bf16(a, b, c, 0, 0, 0);
}
static __device__ __forceinline__ f32x16 mfma32(bf16x8 a, bf16x8 b, f32x16 c) {
    return __builtin_amdgcn_mfma_f32_32x32x16_bf16(a, b, c, 0, 0, 0);
}
static __device__ __forceinline__ unsigned cvt_pk_bf16(float lo, float hi) {
    unsigned r;
    asm("v_cvt_pk_bf16_f32 %0, %1, %2" : "=v"(r) : "v"(lo), "v"(hi));
    return r;
}

// async 16B/lane global->LDS DMA.  lds base is WAVE-UNIFORM; lane i's 16 B
// land at base + i*16.  Side-effecting intrinsic -> compiler cannot sink it.
static __device__ __forceinline__ void async_ld16(const void* g, void* l) {
    __builtin_amdgcn_global_load_lds(
        (const __attribute__((address_space(1))) void*)g,
        (__attribute__((address_space(3))) void*)l, 16, 0, 0);
}

// raw barrier (NO implicit vmcnt(0) drain, unlike __syncthreads)
static __device__ __forceinline__ void barx() {
    asm volatile("s_barrier" ::: "memory");
}
// counted vmcnt waits (T4); runtime n resolves to a literal branch
static __device__ __forceinline__ void wait_vm(int n) {
    if      (n >= 8) asm volatile("s_waitcnt vmcnt(8)" ::: "memory");
    else if (n >= 6) asm volatile("s_waitcnt vmcnt(6)" ::: "memory");
    else if (n >= 4) asm volatile("s_waitcnt vmcnt(4)" ::: "memory");
    else if (n >= 2) asm volatile("s_waitcnt vmcnt(2)" ::: "memory");
    else             asm volatile("s_waitcnt vmcnt(0)" ::: "memory");
}

// ---------------------------------------------------------------------------
// Kernel 0: pack W -> Wt fragment-major (verified r4): element (jg,h,lane,e)
// at ((jg*32+h)*64 + lane)*8 + e holds W_which[k][h_out]*s with
// h_out = (jg&3)*16 + (lane&15), k = h*32 + (lane>>4)*8 + e.
// A wave's whole mfma B-fragment is ONE contiguous 1 KB load.
// ---------------------------------------------------------------------------
__global__ __launch_bounds__(256) void pack_w(
    const float* __restrict__ Wq, const float* __restrict__ Wk,
    const float* __restrict__ Wv, bf16* __restrict__ Wt)
{
    __shared__ float Wl[128][68];             // stride 68: 16B-aligned rows
    const int which = blockIdx.x >> 3;        // 0..2
    const int kb    = blockIdx.x & 7;         // k-block of 128
    const int t     = threadIdx.x;
    const float* W = which == 0 ? Wq : (which == 1 ? Wk : Wv);
    const float s = which == 0 ? QSCALE : 1.0f;

    const float4* Wf = (const float4*)(W + (size_t)kb * 128 * 64);
    #pragma unroll
    for (int i = 0; i < 8; ++i) {             // 32 KB fully coalesced
        const int f = i * 256 + t;            // float4 idx in 128x64 tile
        float4 w = Wf[f];
        *(float4*)&Wl[f >> 4][(f & 15) * 4] = w;
    }
    __syncthreads();

    const int lanex = t & 63;                 // fragment lane
    const int grp   = t >> 6;                 // 0..3
    const int quad  = lanex >> 4, colx = lanex & 15;
    #pragma unroll
    for (int it = 0; it < 4; ++it) {
        const int seg = it * 4 + grp;         // 0..15 = (jg4,h4)
        const int jg4 = seg >> 2, h4 = seg & 3;
        bf16x8 o;
        #pragma unroll
        for (int e = 0; e < 8; ++e)
            o[e] = (bf16)(Wl[h4 * 32 + quad * 8 + e][jg4 * 16 + colx] * s);
        const int jg = which * 4 + jg4;
        const int h  = kb * 4 + h4;
        *(bf16x8*)(Wt + ((size_t)(jg * 32 + h) * 64 + lanex) * 8) = o;
    }
}

// ---------------------------------------------------------------------------
// Kernel 1: QKV projection v10 = v7 (+) v8.  The two in-session wins were
// never combined: v7's 4-blocks/CU TLP (16-row tile, grid 1024) and v8's
// counted-vmcnt ring (issue distance 3, no full drain at the barrier).
// 16-row tile, ring-4 x 8 KB = 32 KB LDS, __launch_bounds__(256,4) ->
// 16 waves/CU; waits 6/4/2/0 keep 3 chunks of DMA in flight.
// ---------------------------------------------------------------------------
__global__ __launch_bounds__(256, 4) void qkv(
    const float* __restrict__ x, const bf16* __restrict__ Wt,
    const float* __restrict__ bq, const float* __restrict__ bk,
    const float* __restrict__ bv,
    bf16* __restrict__ qb, bf16* __restrict__ kb, bf16* __restrict__ vT)
{
    __shared__ __align__(16) float Xsh[4][2][16][64];   // 32 KB ring

    const int tid  = threadIdx.x;
    const int lane = tid & 63;
    const int wvid = tid >> 6;            // 0..3 -> n-triple
    const int quad = lane >> 4;
    const int col  = lane & 15;
    const int row0 = blockIdx.x * 16;     // grid 1024

    const float* xblk = x + (size_t)row0 * CEMB;
    const bf16* wbase[3];
    #pragma unroll
    for (int j = 0; j < 3; ++j)
        wbase[j] = Wt + (size_t)(wvid * 3 + j) * 32 * 64 * 8 + (size_t)lane * 8;

    // DMA stage: per 64-col half, wave issues 1 wave-load of 4 rows (1 KB)
    const int sr = lane >> 4;             // row within wave-load 0..3
    const int ss = lane & 15;             // LDS granule slot
    auto stage = [&](int ci, int bufi) {
        #pragma unroll
        for (int h2 = 0; h2 < 2; ++h2) {
            const int r = wvid * 4 + sr;  // 0..15
            const int c = ss ^ (r & 7);   // global granule (16B = 4 fp32)
            async_ld16(xblk + (size_t)r * CEMB + ci * 128 + h2 * 64 + c * 4,
                       &Xsh[bufi][h2][wvid * 4][0]);
        }
    };

    f32x4 acc[3] = {};                    // [n-tile]
    const int c7 = col & 7;

    stage(0, 0); stage(1, 1); stage(2, 2);
    #pragma unroll
    for (int ci = 0; ci < 8; ++ci) {      // 8 chunks of 128 k
        barx();                           // readers of chunk ci-1 finished
        if (ci + 3 < 8) stage(ci + 3, (ci + 3) & 3);
        wait_vm(2 * (ci <= 4 ? 3 : 7 - ci));  // own stage(ci) retired
        barx();                           // all waves' chunk-ci DMA retired
        const int buf = ci & 3;

        #pragma unroll
        for (int kk = 0; kk < 4; ++kk) {  // 4 x 32-k steps
            const int h  = ci * 4 + kk;
            const int hf = kk >> 1;       // which 64-col half
            const int kl = kk & 1;
            bf16x8 Bv[3];
            #pragma unroll
            for (int j = 0; j < 3; ++j)
                Bv[j] = *(const bf16x8*)(wbase[j] + (size_t)h * 512);
            const int g0 = kl * 8 + quad * 2;
            float4 a0 = *(const float4*)&Xsh[buf][hf][col][(g0 ^ c7) * 4];
            float4 a1 = *(const float4*)&Xsh[buf][hf][col][((g0 + 1) ^ c7) * 4];
            bf16x8 af;
            af[0]=(bf16)a0.x; af[1]=(bf16)a0.y; af[2]=(bf16)a0.z; af[3]=(bf16)a0.w;
            af[4]=(bf16)a1.x; af[5]=(bf16)a1.y; af[6]=(bf16)a1.z; af[7]=(bf16)a1.w;
            #pragma unroll
            for (int j = 0; j < 3; ++j)
                acc[j] = mfma16(af, Bv[j], acc[j]);
        }
    }

    const float* bias[3] = {bq, bk, bv};
    #pragma unroll
    for (int j = 0; j < 3; ++j) {
        const int jg = wvid * 3 + j;      // global n-tile 0..11
        const int which = jg >> 2;
        const int h = (jg & 3) * 16 + col;
        float bb = bias[which][h];
        if (which == 0) bb *= QSCALE;
        if (which < 2) {
            bf16* dst = which == 0 ? qb : kb;
            #pragma unroll
            for (int r = 0; r < 4; ++r) {
                const int trow = row0 + quad * 4 + r;
                dst[(size_t)trow * HEAD + h] = (bf16)(acc[j][r] + bb);
            }
        } else {                          // v -> vT[b][h][t], 4 contig t
            bf16x4 pv;
            #pragma unroll
            for (int r = 0; r < 4; ++r) pv[r] = (bf16)(acc[j][r] + bb);
            const int trow0 = row0 + quad * 4;
            const int bb_   = trow0 >> 12;
            const int tt    = trow0 & (TLEN - 1);
            *(bf16x4*)(vT + ((size_t)(bb_ * HEAD + h)) * TLEN + tt) = pv;
        }
    }
}

// ---------------------------------------------------------------------------
// Kernel 2: attention v6.  Compute identical to verified v5b (32x32x16 MFMA,
// in-register T12 P relayout).  Staging upgraded to ring-3 + counted vmcnt:
// prefetch distance 2 (~1400cy > 900cy HBM latency), barx + wait_vm(own)
// replaces the per-chunk __syncthreads vmcnt(0) drain.  Compute is pure-LDS
// (no global loads) so the counted stream is unpolluted.  All ds_reads are
// MFMA-consumed in-iteration -> lgkmcnt-safe at the raw barrier.
// ---------------------------------------------------------------------------
__global__ __launch_bounds__(256, 2) void attn(
    const bf16* __restrict__ qb, const bf16* __restrict__ kb,
    const bf16* __restrict__ vT,
    bf16* __restrict__ opart, float* __restrict__ lpart,
    float* __restrict__ out, int nsplit, int lg2S)
{
    __shared__ __align__(16) bf16 Ksh[3][64][64];   // 24 KB ring
    __shared__ __align__(16) bf16 Vsh[3][64][64];   // 24 KB ring (V^T: [h][s])

    const int tid  = threadIdx.x;
    const int lane = tid & 63;
    const int wvid = tid >> 6;
    const int l31  = lane & 31;
    const int b5   = lane >> 5;

    int b, sp, qtile;
    {
        const int id = blockIdx.x;
        if (nsplit >= 2) {
            const int cpx = (BATCH << lg2S) >> 3;   // combos per XCD
            const int idx = id >> 3;
            const int combo = (id & 7) * cpx + (idx >> 4);
            qtile = idx & 15;
            b = combo >> lg2S;
            sp = combo & (nsplit - 1);
        } else {
            qtile = id & 15; b = id >> 4; sp = 0;
        }
    }
    const int q0 = qtile * 256 + wvid * 64;
    const size_t rowbase = (size_t)b * TLEN + q0;

    // Q B-frags (32x32x16): lane holds Q[q = l31][h = 16m + 8*b5 .. +7]
    bf16x8 qf[2][4];
    #pragma unroll
    for (int qt = 0; qt < 2; ++qt)
        #pragma unroll
        for (int m = 0; m < 4; ++m)
            qf[qt][m] = *(const bf16x8*)
                (qb + (rowbase + qt * 32 + l31) * HEAD + m * 16 + b5 * 8);

    const bf16* kbB = kb + (size_t)b * TLEN * HEAD;
    const bf16* vTB = vT + (size_t)b * HEAD * TLEN;

    f32x16 o[2][2] = {};                  // [qt][ht]
    float lsum[2] = {0.f, 0.f};

    const int slen = TLEN >> lg2S;
    const int sbeg = sp * slen;
    const int nch  = slen / 64;

    const int r8 = lane >> 3;            // 0..7
    const int s8 = lane & 7;
    auto stage = [&](int s0, int bufi) {
        #pragma unroll
        for (int j = 0; j < 2; ++j) {
            const int r = wvid * 16 + j * 8 + r8;
            const int c = s8 ^ (r & 7);  // global granule (16B = 8 bf16)
            async_ld16(kbB + (size_t)(s0 + r) * HEAD + c * 8,
                       &Ksh[bufi][wvid * 16 + j * 8][0]);
            async_ld16(vTB + (size_t)r * TLEN + s0 + c * 8,
                       &Vsh[bufi][wvid * 16 + j * 8][0]);
        }
    };

    stage(sbeg, 0);
    if (nch > 1) stage(sbeg + 64, 1);
    int buf = 0, sbuf = 2;
    for (int ci = 0; ci < nch; ++ci) {
        barx();                          // readers of chunk ci-1 finished
        if (ci + 2 < nch) stage(sbeg + (ci + 2) * 64, sbuf);
        {                                // own stage(ci) retired
            int n = nch - 1 - ci; if (n > 2) n = 2;
            wait_vm(4 * n);
        }
        barx();                          // all waves' chunk-ci DMA retired

        #pragma unroll
        for (int kt = 0; kt < 2; ++kt) {
            const int kr = kt * 32 + l31;
            const int k7 = kr & 7;
            bf16x8 kf[4];
            #pragma unroll
            for (int m = 0; m < 4; ++m)
                kf[m] = *(const bf16x8*)&Ksh[buf][kr][((2 * m + b5) ^ k7) * 8];

            bf16x8 pb[2][2];             // [qt][kc] PV B-frags
            #pragma unroll
            for (int qt = 0; qt < 2; ++qt) {
                f32x16 st = {};
                #pragma unroll
                for (int m = 0; m < 4; ++m)
                    st = mfma32(kf[m], qf[qt][m], st);
                // D: q = l31, key = kt*32 + (r&3) + 8*(r>>2) + 4*b5
                float e[16];
                #pragma unroll
                for (int r = 0; r < 16; ++r)
                    e[r] = __builtin_amdgcn_exp2f(st[r]);
                float t0 = (e[0] + e[1]) + (e[2] + e[3]);
                float t1 = (e[4] + e[5]) + (e[6] + e[7]);
                float t2 = (e[8] + e[9]) + (e[10] + e[11]);
                float t3 = (e[12] + e[13]) + (e[14] + e[15]);
                lsum[qt] += (t0 + t1) + (t2 + t3);
                unsigned w[8];
                #pragma unroll
                for (int s = 0; s < 8; ++s)
                    w[s] = cvt_pk_bf16(e[2 * s], e[2 * s + 1]);
                #pragma unroll
                for (int kc = 0; kc < 2; ++kc) {
                    auto s02 = __builtin_amdgcn_permlane32_swap(
                        w[4 * kc + 0], w[4 * kc + 2], false, false);
                    auto s13 = __builtin_amdgcn_permlane32_swap(
                        w[4 * kc + 1], w[4 * kc + 3], false, false);
                    u32x4 pw = { (unsigned)s02[0], (unsigned)s13[0],
                                 (unsigned)s02[1], (unsigned)s13[1] };
                    pb[qt][kc] = __builtin_bit_cast(bf16x8, pw);
                }
            }
            #pragma unroll
            for (int ht = 0; ht < 2; ++ht) {
                const int vr = ht * 32 + l31;
                const int v7 = vr & 7;
                #pragma unroll
                for (int kc = 0; kc < 2; ++kc) {
                    bf16x8 vf = *(const bf16x8*)
                        &Vsh[buf][vr][((2 * (2 * kt + kc) + b5) ^ v7) * 8];
                    #pragma unroll
                    for (int qt = 0; qt < 2; ++qt)
                        o[qt][ht] = mfma32(vf, pb[qt][kc], o[qt][ht]);
                }
            }
        }
        buf  = (buf  == 2) ? 0 : buf  + 1;
        sbuf = (sbuf == 2) ? 0 : sbuf + 1;
    }

    #pragma unroll
    for (int qt = 0; qt < 2; ++qt)
        lsum[qt] += __shfl_xor(lsum[qt], 32, 64);

    #pragma unroll
    for (int qt = 0; qt < 2; ++qt) {
        const size_t grow = rowbase + qt * 32 + l31;
        if (nsplit == 1) {
            const float inv = 1.f / lsum[qt];
            float* ob = out + grow * HEAD;
            #pragma unroll
            for (int ht = 0; ht < 2; ++ht)
                #pragma unroll
                for (int g = 0; g < 4; ++g) {
                    f32x4 r = { o[qt][ht][4*g+0] * inv, o[qt][ht][4*g+1] * inv,
                                o[qt][ht][4*g+2] * inv, o[qt][ht][4*g+3] * inv };
                    *(f32x4*)(ob + ht * 32 + g * 8 + b5 * 4) = r;
                }
        } else if (sp == 0) {
            float* ob = out + grow * HEAD;
            #pragma unroll
            for (int ht = 0; ht < 2; ++ht)
                #pragma unroll
                for (int g = 0; g < 4; ++g) {
                    f32x4 r = { o[qt][ht][4*g+0], o[qt][ht][4*g+1],
                                o[qt][ht][4*g+2], o[qt][ht][4*g+3] };
                    *(f32x4*)(ob + ht * 32 + g * 8 + b5 * 4) = r;
                }
            if (lane < 32) lpart[grow] = lsum[qt];
        } else {
            bf16* ob = opart + ((size_t)(sp - 1) * NROWS + grow) * HEAD;
            #pragma unroll
            for (int ht = 0; ht < 2; ++ht)
                #pragma unroll
                for (int g = 0; g < 4; ++g) {
                    bf16x4 r = { (bf16)o[qt][ht][4*g+0], (bf16)o[qt][ht][4*g+1],
                                 (bf16)o[qt][ht][4*g+2], (bf16)o[qt][ht][4*g+3] };
                    *(bf16x4*)(ob + ht * 32 + g * 8 + b5 * 4) = r;
                }
            if (lane < 32) lpart[(size_t)sp * NROWS + grow] = lsum[qt];
        }
    }
}

// ---------------------------------------------------------------------------
// Kernel 3: combine.  Fixed-max partials share one scale -> plain sums.
// ---------------------------------------------------------------------------
__global__ __launch_bounds__(256) void combine(
    const bf16* __restrict__ opart, const float* __restrict__ lpart,
    float* __restrict__ out, int nsplit)
{
    const int gid = blockIdx.x * 256 + threadIdx.x;
    const int row = gid >> 4;
    const int h4  = (gid & 15) * 4;

    float L = 0.f;
    for (int s = 0; s < nsplit; ++s) L += lpart[(size_t)s * NROWS + row];
    f32x4 O = *(const f32x4*)(out + (size_t)row * HEAD + h4);
    for (int s = 1; s < nsplit; ++s) {
        bf16x4 v = *(const bf16x4*)(opart + ((size_t)(s - 1) * NROWS + row) * HEAD + h4);
        O[0] += (float)v[0]; O[1] += (float)v[1];
        O[2] += (float)v[2]; O[3] += (float)v[3];
    }
    f32x4 r = O * (1.f / L);
    *(f32x4*)(out + (size_t)row * HEAD + h4) = r;
}

// ---------------------------------------------------------------------------
extern "C" void kernel_launch(void* const* d_in, const int* in_sizes, int n_in,
                              void* d_out, int out_size, void* d_ws, size_t ws_size,
                              hipStream_t stream) {
    const float* x  = (const float*)d_in[0];
    const float* Wq = (const float*)d_in[1];
    const float* bq = (const float*)d_in[2];
    const float* Wk = (const float*)d_in[3];
    const float* bk = (const float*)d_in[4];
    const float* Wv = (const float*)d_in[5];
    const float* bv = (const float*)d_in[6];
    float* out = (float*)d_out;

    const size_t n_tok = (size_t)NROWS * HEAD;          // 1,048,576
    char* ws = (char*)d_ws;
    bf16* qb = (bf16*)ws;
    bf16* kb = qb + n_tok;
    bf16* vT = kb + n_tok;
    bf16* Wt = vT + n_tok;
    const size_t base = 3 * n_tok * sizeof(bf16) + 192 * CEMB * sizeof(bf16);

    auto need = [&](int S) {
        return base + (size_t)(S - 1) * n_tok * sizeof(bf16)
                    + (size_t)S * NROWS * sizeof(float);
    };
    int S = 1, lg2S = 0;
    if      (ws_size >= need(8)) { S = 8; lg2S = 3; }
    else if (ws_size >= need(4)) { S = 4; lg2S = 2; }
    else if (ws_size >= need(2)) { S = 2; lg2S = 1; }
    bf16*  opart = Wt + 192 * CEMB;
    float* lpart = (float*)(opart + (size_t)(S - 1) * n_tok);

    pack_w<<<dim3(24), dim3(256), 0, stream>>>(Wq, Wk, Wv, Wt);
    qkv<<<dim3(1024), dim3(256), 0, stream>>>(x, Wt, bq, bk, bv, qb, kb, vT);
    attn<<<dim3(16 * BATCH * S), dim3(256), 0, stream>>>(
        qb, kb, vT, opart, lpart, out, S, lg2S);
    if (S > 1)
        combine<<<dim3((NROWS * 16) / 256), dim3(256), 0, stream>>>(
            opart, lpart, out, S);
}

// Round 9
// 143.558 us; speedup vs baseline: 1.0573x; 1.0573x over previous
//
#include <hip/hip_runtime.h>
#include <hip/hip_bf16.h>
#include <cmath>

#define BATCH 4
#define TLEN  4096
#define CEMB  1024
#define HEAD  64
#define NROWS (BATCH * TLEN)          // 16384 token rows

typedef __bf16 bf16;
typedef __attribute__((ext_vector_type(8))) __bf16 bf16x8;
typedef __attribute__((ext_vector_type(4))) __bf16 bf16x4;
typedef __attribute__((ext_vector_type(4))) float f32x4;
typedef __attribute__((ext_vector_type(16))) float f32x16;
typedef __attribute__((ext_vector_type(4))) unsigned u32x4;

#define QSCALE 0.1803368801111204f    // (1/sqrt(64)) * log2(e)

static __device__ __forceinline__ f32x4 mfma16(bf16x8 a, bf16x8 b, f32x4 c) {
    return __builtin_amdgcn_mfma_f32_16x16x32_bf16(a, b, c, 0, 0, 0);
}
static __device__ __forceinline__ f32x16 mfma32(bf16x8 a, bf16x8 b, f32x16 c) {
    return __builtin_amdgcn_mfma_f32_32x32x16_bf16(a, b, c, 0, 0, 0);
}
static __device__ __forceinline__ unsigned cvt_pk_bf16(float lo, float hi) {
    unsigned r;
    asm("v_cvt_pk_bf16_f32 %0, %1, %2" : "=v"(r) : "v"(lo), "v"(hi));
    return r;
}

// async 16B/lane global->LDS DMA.  lds base is WAVE-UNIFORM; lane i's 16 B
// land at base + i*16.  Side-effecting intrinsic -> compiler cannot sink it.
static __device__ __forceinline__ void async_ld16(const void* g, void* l) {
    __builtin_amdgcn_global_load_lds(
        (const __attribute__((address_space(1))) void*)g,
        (__attribute__((address_space(3))) void*)l, 16, 0, 0);
}

// raw barrier (NO implicit vmcnt(0) drain, unlike __syncthreads)
static __device__ __forceinline__ void barx() {
    asm volatile("s_barrier" ::: "memory");
}
// counted vmcnt waits (T4); n is compile-time under unroll
static __device__ __forceinline__ void wait_vm(int n) {
    if      (n >= 10) asm volatile("s_waitcnt vmcnt(10)" ::: "memory");
    else if (n >= 6)  asm volatile("s_waitcnt vmcnt(6)"  ::: "memory");
    else              asm volatile("s_waitcnt vmcnt(0)"  ::: "memory");
}

// ---------------------------------------------------------------------------
// Kernel 0: pack W -> Wt fragment-major (verified r4): element (jg,h,lane,e)
// at ((jg*32+h)*64 + lane)*8 + e holds W_which[k][h_out]*s with
// h_out = (jg&3)*16 + (lane&15), k = h*32 + (lane>>4)*8 + e.
// A wave's whole mfma B-fragment is ONE contiguous 1 KB load.
// ---------------------------------------------------------------------------
__global__ __launch_bounds__(256) void pack_w(
    const float* __restrict__ Wq, const float* __restrict__ Wk,
    const float* __restrict__ Wv, bf16* __restrict__ Wt)
{
    __shared__ float Wl[128][68];             // stride 68: 16B-aligned rows
    const int which = blockIdx.x >> 3;        // 0..2
    const int kb    = blockIdx.x & 7;         // k-block of 128
    const int t     = threadIdx.x;
    const float* W = which == 0 ? Wq : (which == 1 ? Wk : Wv);
    const float s = which == 0 ? QSCALE : 1.0f;

    const float4* Wf = (const float4*)(W + (size_t)kb * 128 * 64);
    #pragma unroll
    for (int i = 0; i < 8; ++i) {             // 32 KB fully coalesced
        const int f = i * 256 + t;            // float4 idx in 128x64 tile
        float4 w = Wf[f];
        *(float4*)&Wl[f >> 4][(f & 15) * 4] = w;
    }
    __syncthreads();

    const int lanex = t & 63;                 // fragment lane
    const int grp   = t >> 6;                 // 0..3
    const int quad  = lanex >> 4, colx = lanex & 15;
    #pragma unroll
    for (int it = 0; it < 4; ++it) {
        const int seg = it * 4 + grp;         // 0..15 = (jg4,h4)
        const int jg4 = seg >> 2, h4 = seg & 3;
        bf16x8 o;
        #pragma unroll
        for (int e = 0; e < 8; ++e)
            o[e] = (bf16)(Wl[h4 * 32 + quad * 8 + e][jg4 * 16 + colx] * s);
        const int jg = which * 4 + jg4;
        const int h  = kb * 4 + h4;
        *(bf16x8*)(Wt + ((size_t)(jg * 32 + h) * 64 + lanex) * 8) = o;
    }
}

// ---------------------------------------------------------------------------
// Kernel 1: QKV projection v11 = v9's pipeline at 3 blocks/CU.  32-row tile
// (Wt L2 traffic stays 197 MB: r8 showed 16-row's 2x Wt traffic costs ~6us),
// ring-3 LDS (48 KB -> 3 blocks/CU, __launch_bounds__(256,3), 12 waves/CU),
// stage issue distance 2, Bv prefetched at HALF-chunk granularity
// (bvA/bvB[2][3] = 48 VGPR, fits the 170-VGPR cap without spills).
// Issue order per iter: barx; bvB(ci,h1); stage(ci+2); wait(10); barx;
// compute h0 (bvA); load bvA(ci+1,h0); compute h1 (bvB).
// Steady-state wait 10 = bvB(6)+stage(4) newer than bvA; compiler's own
// bvB wait also lands at vmcnt(10) -> fresh stage stays in flight.
// ---------------------------------------------------------------------------
__global__ __launch_bounds__(256, 3) void qkv(
    const float* __restrict__ x, const bf16* __restrict__ Wt,
    const float* __restrict__ bq, const float* __restrict__ bk,
    const float* __restrict__ bv_,
    bf16* __restrict__ qb, bf16* __restrict__ kb, bf16* __restrict__ vT)
{
    __shared__ __align__(16) float Xsh[3][2][32][64];   // 48 KB ring

    const int tid  = threadIdx.x;
    const int lane = tid & 63;
    const int wvid = tid >> 6;            // 0..3 -> n-triple
    const int quad = lane >> 4;
    const int col  = lane & 15;
    const int row0 = blockIdx.x * 32;     // grid 512

    const float* xblk = x + (size_t)row0 * CEMB;
    const bf16* wbase[3];
    #pragma unroll
    for (int j = 0; j < 3; ++j)
        wbase[j] = Wt + (size_t)(wvid * 3 + j) * 32 * 64 * 8 + (size_t)lane * 8;

    // DMA stage: 4 wave-loads (1 KB each) per chunk per wave
    const int sr = lane >> 4;             // row within wave-load 0..3
    const int ss = lane & 15;             // LDS granule slot
    auto stage = [&](int ci, int bufi) {
        #pragma unroll
        for (int h2 = 0; h2 < 2; ++h2)
            #pragma unroll
            for (int j = 0; j < 2; ++j) {
                const int r = wvid * 8 + j * 4 + sr;
                const int c = ss ^ (r & 7);   // global granule (16B = 4 fp32)
                async_ld16(xblk + (size_t)r * CEMB + ci * 128 + h2 * 64 + c * 4,
                           &Xsh[bufi][h2][wvid * 8 + j * 4][0]);
            }
    };

    f32x4 acc[2][3] = {};                 // [row-tile][n-tile]
    bf16x8 bvA[2][3], bvB[2][3];          // half-chunk B-frags (48 VGPR)
    const int c7 = col & 7;

    auto loadBv = [&](int hb, bf16x8 (&tgt)[2][3]) {
        #pragma unroll
        for (int kl = 0; kl < 2; ++kl)
            #pragma unroll
            for (int j = 0; j < 3; ++j)
                tgt[kl][j] = *(const bf16x8*)(wbase[j] + (size_t)(hb + kl) * 512);
    };

    // prologue: stage 0,1; bvA = chunk0 half0
    stage(0, 0); stage(1, 1);
    loadBv(0, bvA);

    #pragma unroll
    for (int ci = 0; ci < 8; ++ci) {      // 8 chunks of 128 k
        barx();                           // readers of chunk ci-1 finished
        loadBv(ci * 4 + 2, bvB);          // current chunk half1
        if (ci + 2 < 8) stage(ci + 2, (ci + 2) % 3);
        wait_vm(ci <= 5 ? 10 : 6);        // own stage(ci)+bvA retired
        barx();                           // all waves' chunk-ci DMA retired
        const int buf = ci % 3;

        // half0: kk = 0,1 with bvA
        #pragma unroll
        for (int kl = 0; kl < 2; ++kl) {
            const int g0 = kl * 8 + quad * 2;
            #pragma unroll
            for (int rt = 0; rt < 2; ++rt) {
                const int r = rt * 16 + col;
                float4 a0 = *(const float4*)&Xsh[buf][0][r][(g0 ^ c7) * 4];
                float4 a1 = *(const float4*)&Xsh[buf][0][r][((g0 + 1) ^ c7) * 4];
                bf16x8 af;
                af[0]=(bf16)a0.x; af[1]=(bf16)a0.y; af[2]=(bf16)a0.z; af[3]=(bf16)a0.w;
                af[4]=(bf16)a1.x; af[5]=(bf16)a1.y; af[6]=(bf16)a1.z; af[7]=(bf16)a1.w;
                #pragma unroll
                for (int j = 0; j < 3; ++j)
                    acc[rt][j] = mfma16(af, bvA[kl][j], acc[rt][j]);
            }
        }
        // prefetch next chunk half0 into bvA (reg WAR keeps order vs reads)
        if (ci + 1 < 8) loadBv((ci + 1) * 4, bvA);
        // half1: kk = 2,3 with bvB
        #pragma unroll
        for (int kl = 0; kl < 2; ++kl) {
            const int g0 = kl * 8 + quad * 2;
            #pragma unroll
            for (int rt = 0; rt < 2; ++rt) {
                const int r = rt * 16 + col;
                float4 a0 = *(const float4*)&Xsh[buf][1][r][(g0 ^ c7) * 4];
                float4 a1 = *(const float4*)&Xsh[buf][1][r][((g0 + 1) ^ c7) * 4];
                bf16x8 af;
                af[0]=(bf16)a0.x; af[1]=(bf16)a0.y; af[2]=(bf16)a0.z; af[3]=(bf16)a0.w;
                af[4]=(bf16)a1.x; af[5]=(bf16)a1.y; af[6]=(bf16)a1.z; af[7]=(bf16)a1.w;
                #pragma unroll
                for (int j = 0; j < 3; ++j)
                    acc[rt][j] = mfma16(af, bvB[kl][j], acc[rt][j]);
            }
        }
    }

    const float* bias[3] = {bq, bk, bv_};
    #pragma unroll
    for (int j = 0; j < 3; ++j) {
        const int jg = wvid * 3 + j;      // global n-tile 0..11
        const int which = jg >> 2;
        const int h = (jg & 3) * 16 + col;
        float bb = bias[which][h];
        if (which == 0) bb *= QSCALE;
        #pragma unroll
        for (int rt = 0; rt < 2; ++rt) {
            if (which < 2) {
                bf16* dst = which == 0 ? qb : kb;
                #pragma unroll
                for (int r = 0; r < 4; ++r) {
                    const int trow = row0 + rt * 16 + quad * 4 + r;
                    dst[(size_t)trow * HEAD + h] = (bf16)(acc[rt][j][r] + bb);
                }
            } else {                      // v -> vT[b][h][t], 4 contig t
                bf16x4 pv;
                #pragma unroll
                for (int r = 0; r < 4; ++r) pv[r] = (bf16)(acc[rt][j][r] + bb);
                const int trow0 = row0 + rt * 16 + quad * 4;
                const int bb_   = trow0 >> 12;
                const int tt    = trow0 & (TLEN - 1);
                *(bf16x4*)(vT + ((size_t)(bb_ * HEAD + h)) * TLEN + tt) = pv;
            }
        }
    }
}

// ---------------------------------------------------------------------------
// Kernel 2: attention v5b (reverted to r7 verbatim, verified).  32x32x16
// MFMA; in-register P relayout via cvt_pk + permlane32_swap (T12); K/V
// staged via global_load_lds DMA, double-buffered; fixed-max softmax.
// ---------------------------------------------------------------------------
__global__ __launch_bounds__(256, 2) void attn(
    const bf16* __restrict__ qb, const bf16* __restrict__ kb,
    const bf16* __restrict__ vT,
    bf16* __restrict__ opart, float* __restrict__ lpart,
    float* __restrict__ out, int nsplit, int lg2S)
{
    __shared__ __align__(16) bf16 Ksh[2][64][64];   // 16 KB
    __shared__ __align__(16) bf16 Vsh[2][64][64];   // 16 KB (V^T: [h][s])

    const int tid  = threadIdx.x;
    const int lane = tid & 63;
    const int wvid = tid >> 6;
    const int l31  = lane & 31;
    const int b5   = lane >> 5;

    int b, sp, qtile;
    {
        const int id = blockIdx.x;
        if (nsplit >= 2) {
            const int cpx = (BATCH << lg2S) >> 3;   // combos per XCD
            const int idx = id >> 3;
            const int combo = (id & 7) * cpx + (idx >> 4);
            qtile = idx & 15;
            b = combo >> lg2S;
            sp = combo & (nsplit - 1);
        } else {
            qtile = id & 15; b = id >> 4; sp = 0;
        }
    }
    const int q0 = qtile * 256 + wvid * 64;
    const size_t rowbase = (size_t)b * TLEN + q0;

    // Q B-frags (32x32x16): lane holds Q[q = l31][h = 16m + 8*b5 .. +7]
    bf16x8 qf[2][4];
    #pragma unroll
    for (int qt = 0; qt < 2; ++qt)
        #pragma unroll
        for (int m = 0; m < 4; ++m)
            qf[qt][m] = *(const bf16x8*)
                (qb + (rowbase + qt * 32 + l31) * HEAD + m * 16 + b5 * 8);

    const bf16* kbB = kb + (size_t)b * TLEN * HEAD;
    const bf16* vTB = vT + (size_t)b * HEAD * TLEN;

    f32x16 o[2][2] = {};                  // [qt][ht]
    float lsum[2] = {0.f, 0.f};

    const int slen = TLEN >> lg2S;
    const int sbeg = sp * slen;
    const int nch  = slen / 64;

    const int r8 = lane >> 3;            // 0..7
    const int s8 = lane & 7;
    auto stage = [&](int s0, int bufi) {
        #pragma unroll
        for (int j = 0; j < 2; ++j) {
            const int r = wvid * 16 + j * 8 + r8;
            const int c = s8 ^ (r & 7);  // global granule (16B = 8 bf16)
            async_ld16(kbB + (size_t)(s0 + r) * HEAD + c * 8,
                       &Ksh[bufi][wvid * 16 + j * 8][0]);
            async_ld16(vTB + (size_t)r * TLEN + s0 + c * 8,
                       &Vsh[bufi][wvid * 16 + j * 8][0]);
        }
    };

    stage(sbeg, 0);
    int buf = 0;
    for (int ci = 0; ci < nch; ++ci) {
        __syncthreads();                 // implicit vmcnt(0): DMA(ci) visible
        if (ci + 1 < nch) stage(sbeg + (ci + 1) * 64, buf ^ 1);

        #pragma unroll
        for (int kt = 0; kt < 2; ++kt) {
            const int kr = kt * 32 + l31;
            const int k7 = kr & 7;
            bf16x8 kf[4];
            #pragma unroll
            for (int m = 0; m < 4; ++m)
                kf[m] = *(const bf16x8*)&Ksh[buf][kr][((2 * m + b5) ^ k7) * 8];

            bf16x8 pb[2][2];             // [qt][kc] PV B-frags
            #pragma unroll
            for (int qt = 0; qt < 2; ++qt) {
                f32x16 st = {};
                #pragma unroll
                for (int m = 0; m < 4; ++m)
                    st = mfma32(kf[m], qf[qt][m], st);
                // D: q = l31, key = kt*32 + (r&3) + 8*(r>>2) + 4*b5
                float e[16];
                #pragma unroll
                for (int r = 0; r < 16; ++r)
                    e[r] = __builtin_amdgcn_exp2f(st[r]);
                float t0 = (e[0] + e[1]) + (e[2] + e[3]);
                float t1 = (e[4] + e[5]) + (e[6] + e[7]);
                float t2 = (e[8] + e[9]) + (e[10] + e[11]);
                float t3 = (e[12] + e[13]) + (e[14] + e[15]);
                lsum[qt] += (t0 + t1) + (t2 + t3);
                unsigned w[8];
                #pragma unroll
                for (int s = 0; s < 8; ++s)
                    w[s] = cvt_pk_bf16(e[2 * s], e[2 * s + 1]);
                #pragma unroll
                for (int kc = 0; kc < 2; ++kc) {
                    auto s02 = __builtin_amdgcn_permlane32_swap(
                        w[4 * kc + 0], w[4 * kc + 2], false, false);
                    auto s13 = __builtin_amdgcn_permlane32_swap(
                        w[4 * kc + 1], w[4 * kc + 3], false, false);
                    u32x4 pw = { (unsigned)s02[0], (unsigned)s13[0],
                                 (unsigned)s02[1], (unsigned)s13[1] };
                    pb[qt][kc] = __builtin_bit_cast(bf16x8, pw);
                }
            }
            #pragma unroll
            for (int ht = 0; ht < 2; ++ht) {
                const int vr = ht * 32 + l31;
                const int v7 = vr & 7;
                #pragma unroll
                for (int kc = 0; kc < 2; ++kc) {
                    bf16x8 vf = *(const bf16x8*)
                        &Vsh[buf][vr][((2 * (2 * kt + kc) + b5) ^ v7) * 8];
                    #pragma unroll
                    for (int qt = 0; qt < 2; ++qt)
                        o[qt][ht] = mfma32(vf, pb[qt][kc], o[qt][ht]);
                }
            }
        }
        buf ^= 1;
    }

    #pragma unroll
    for (int qt = 0; qt < 2; ++qt)
        lsum[qt] += __shfl_xor(lsum[qt], 32, 64);

    #pragma unroll
    for (int qt = 0; qt < 2; ++qt) {
        const size_t grow = rowbase + qt * 32 + l31;
        if (nsplit == 1) {
            const float inv = 1.f / lsum[qt];
            float* ob = out + grow * HEAD;
            #pragma unroll
            for (int ht = 0; ht < 2; ++ht)
                #pragma unroll
                for (int g = 0; g < 4; ++g) {
                    f32x4 r = { o[qt][ht][4*g+0] * inv, o[qt][ht][4*g+1] * inv,
                                o[qt][ht][4*g+2] * inv, o[qt][ht][4*g+3] * inv };
                    *(f32x4*)(ob + ht * 32 + g * 8 + b5 * 4) = r;
                }
        } else if (sp == 0) {
            float* ob = out + grow * HEAD;
            #pragma unroll
            for (int ht = 0; ht < 2; ++ht)
                #pragma unroll
                for (int g = 0; g < 4; ++g) {
                    f32x4 r = { o[qt][ht][4*g+0], o[qt][ht][4*g+1],
                                o[qt][ht][4*g+2], o[qt][ht][4*g+3] };
                    *(f32x4*)(ob + ht * 32 + g * 8 + b5 * 4) = r;
                }
            if (lane < 32) lpart[grow] = lsum[qt];
        } else {
            bf16* ob = opart + ((size_t)(sp - 1) * NROWS + grow) * HEAD;
            #pragma unroll
            for (int ht = 0; ht < 2; ++ht)
                #pragma unroll
                for (int g = 0; g < 4; ++g) {
                    bf16x4 r = { (bf16)o[qt][ht][4*g+0], (bf16)o[qt][ht][4*g+1],
                                 (bf16)o[qt][ht][4*g+2], (bf16)o[qt][ht][4*g+3] };
                    *(bf16x4*)(ob + ht * 32 + g * 8 + b5 * 4) = r;
                }
            if (lane < 32) lpart[(size_t)sp * NROWS + grow] = lsum[qt];
        }
    }
}

// ---------------------------------------------------------------------------
// Kernel 3: combine.  Fixed-max partials share one scale -> plain sums.
// ---------------------------------------------------------------------------
__global__ __launch_bounds__(256) void combine(
    const bf16* __restrict__ opart, const float* __restrict__ lpart,
    float* __restrict__ out, int nsplit)
{
    const int gid = blockIdx.x * 256 + threadIdx.x;
    const int row = gid >> 4;
    const int h4  = (gid & 15) * 4;

    float L = 0.f;
    for (int s = 0; s < nsplit; ++s) L += lpart[(size_t)s * NROWS + row];
    f32x4 O = *(const f32x4*)(out + (size_t)row * HEAD + h4);
    for (int s = 1; s < nsplit; ++s) {
        bf16x4 v = *(const bf16x4*)(opart + ((size_t)(s - 1) * NROWS + row) * HEAD + h4);
        O[0] += (float)v[0]; O[1] += (float)v[1];
        O[2] += (float)v[2]; O[3] += (float)v[3];
    }
    f32x4 r = O * (1.f / L);
    *(f32x4*)(out + (size_t)row * HEAD + h4) = r;
}

// ---------------------------------------------------------------------------
extern "C" void kernel_launch(void* const* d_in, const int* in_sizes, int n_in,
                              void* d_out, int out_size, void* d_ws, size_t ws_size,
                              hipStream_t stream) {
    const float* x  = (const float*)d_in[0];
    const float* Wq = (const float*)d_in[1];
    const float* bq = (const float*)d_in[2];
    const float* Wk = (const float*)d_in[3];
    const float* bk = (const float*)d_in[4];
    const float* Wv = (const float*)d_in[5];
    const float* bv = (const float*)d_in[6];
    float* out = (float*)d_out;

    const size_t n_tok = (size_t)NROWS * HEAD;          // 1,048,576
    char* ws = (char*)d_ws;
    bf16* qb = (bf16*)ws;
    bf16* kb = qb + n_tok;
    bf16* vT = kb + n_tok;
    bf16* Wt = vT + n_tok;
    const size_t base = 3 * n_tok * sizeof(bf16) + 192 * CEMB * sizeof(bf16);

    auto need = [&](int S) {
        return base + (size_t)(S - 1) * n_tok * sizeof(bf16)
                    + (size_t)S * NROWS * sizeof(float);
    };
    int S = 1, lg2S = 0;
    if      (ws_size >= need(8)) { S = 8; lg2S = 3; }
    else if (ws_size >= need(4)) { S = 4; lg2S = 2; }
    else if (ws_size >= need(2)) { S = 2; lg2S = 1; }
    bf16*  opart = Wt + 192 * CEMB;
    float* lpart = (float*)(opart + (size_t)(S - 1) * n_tok);

    pack_w<<<dim3(24), dim3(256), 0, stream>>>(Wq, Wk, Wv, Wt);
    qkv<<<dim3(512), dim3(256), 0, stream>>>(x, Wt, bq, bk, bv, qb, kb, vT);
    attn<<<dim3(16 * BATCH * S), dim3(256), 0, stream>>>(
        qb, kb, vT, opart, lpart, out, S, lg2S);
    if (S > 1)
        combine<<<dim3((NROWS * 16) / 256), dim3(256), 0, stream>>>(
            opart, lpart, out, S);
}

// Round 10
// 142.954 us; speedup vs baseline: 1.0618x; 1.0042x over previous
//
#include <hip/hip_runtime.h>
#include <hip/hip_bf16.h>
#include <cmath>

#define BATCH 4
#define TLEN  4096
#define CEMB  1024
#define HEAD  64
#define NROWS (BATCH * TLEN)          // 16384 token rows

typedef __bf16 bf16;
typedef __attribute__((ext_vector_type(8))) __bf16 bf16x8;
typedef __attribute__((ext_vector_type(4))) __bf16 bf16x4;
typedef __attribute__((ext_vector_type(4))) float f32x4;
typedef __attribute__((ext_vector_type(16))) float f32x16;
typedef __attribute__((ext_vector_type(4))) unsigned u32x4;

#define QSCALE 0.1803368801111204f    // (1/sqrt(64)) * log2(e)

static __device__ __forceinline__ f32x4 mfma16(bf16x8 a, bf16x8 b, f32x4 c) {
    return __builtin_amdgcn_mfma_f32_16x16x32_bf16(a, b, c, 0, 0, 0);
}
static __device__ __forceinline__ f32x16 mfma32(bf16x8 a, bf16x8 b, f32x16 c) {
    return __builtin_amdgcn_mfma_f32_32x32x16_bf16(a, b, c, 0, 0, 0);
}
static __device__ __forceinline__ unsigned cvt_pk_bf16(float lo, float hi) {
    unsigned r;
    asm("v_cvt_pk_bf16_f32 %0, %1, %2" : "=v"(r) : "v"(lo), "v"(hi));
    return r;
}

// async 16B/lane global->LDS DMA.  lds base is WAVE-UNIFORM; lane i's 16 B
// land at base + i*16.  Side-effecting intrinsic -> compiler cannot sink it.
static __device__ __forceinline__ void async_ld16(const void* g, void* l) {
    __builtin_amdgcn_global_load_lds(
        (const __attribute__((address_space(1))) void*)g,
        (__attribute__((address_space(3))) void*)l, 16, 0, 0);
}

// raw barrier (NO implicit vmcnt(0) drain, unlike __syncthreads)
static __device__ __forceinline__ void barx() {
    asm volatile("s_barrier" ::: "memory");
}
// counted vmcnt waits (T4); n is compile-time under unroll
static __device__ __forceinline__ void wait_vm(int n) {
    if      (n >= 10) asm volatile("s_waitcnt vmcnt(10)" ::: "memory");
    else if (n >= 8)  asm volatile("s_waitcnt vmcnt(8)"  ::: "memory");
    else if (n >= 6)  asm volatile("s_waitcnt vmcnt(6)"  ::: "memory");
    else if (n >= 4)  asm volatile("s_waitcnt vmcnt(4)"  ::: "memory");
    else              asm volatile("s_waitcnt vmcnt(0)"  ::: "memory");
}

// ---------------------------------------------------------------------------
// Kernel 0: pack W -> Wt fragment-major (verified r4): element (jg,h,lane,e)
// at ((jg*32+h)*64 + lane)*8 + e holds W_which[k][h_out]*s with
// h_out = (jg&3)*16 + (lane&15), k = h*32 + (lane>>4)*8 + e.
// A wave's whole mfma B-fragment is ONE contiguous 1 KB load.
// ---------------------------------------------------------------------------
__global__ __launch_bounds__(256) void pack_w(
    const float* __restrict__ Wq, const float* __restrict__ Wk,
    const float* __restrict__ Wv, bf16* __restrict__ Wt)
{
    __shared__ float Wl[128][68];             // stride 68: 16B-aligned rows
    const int which = blockIdx.x >> 3;        // 0..2
    const int kb    = blockIdx.x & 7;         // k-block of 128
    const int t     = threadIdx.x;
    const float* W = which == 0 ? Wq : (which == 1 ? Wk : Wv);
    const float s = which == 0 ? QSCALE : 1.0f;

    const float4* Wf = (const float4*)(W + (size_t)kb * 128 * 64);
    #pragma unroll
    for (int i = 0; i < 8; ++i) {             // 32 KB fully coalesced
        const int f = i * 256 + t;            // float4 idx in 128x64 tile
        float4 w = Wf[f];
        *(float4*)&Wl[f >> 4][(f & 15) * 4] = w;
    }
    __syncthreads();

    const int lanex = t & 63;                 // fragment lane
    const int grp   = t >> 6;                 // 0..3
    const int quad  = lanex >> 4, colx = lanex & 15;
    #pragma unroll
    for (int it = 0; it < 4; ++it) {
        const int seg = it * 4 + grp;         // 0..15 = (jg4,h4)
        const int jg4 = seg >> 2, h4 = seg & 3;
        bf16x8 o;
        #pragma unroll
        for (int e = 0; e < 8; ++e)
            o[e] = (bf16)(Wl[h4 * 32 + quad * 8 + e][jg4 * 16 + colx] * s);
        const int jg = which * 4 + jg4;
        const int h  = kb * 4 + h4;
        *(bf16x8*)(Wt + ((size_t)(jg * 32 + h) * 64 + lanex) * 8) = o;
    }
}

// ---------------------------------------------------------------------------
// Kernel 1: QKV projection v11 (r9 winner, unchanged).  32-row tile, ring-3
// LDS (48 KB, 3 blocks/CU), stage distance 2, Bv half-chunk reg prefetch.
// ---------------------------------------------------------------------------
__global__ __launch_bounds__(256, 3) void qkv(
    const float* __restrict__ x, const bf16* __restrict__ Wt,
    const float* __restrict__ bq, const float* __restrict__ bk,
    const float* __restrict__ bv_,
    bf16* __restrict__ qb, bf16* __restrict__ kb, bf16* __restrict__ vT)
{
    __shared__ __align__(16) float Xsh[3][2][32][64];   // 48 KB ring

    const int tid  = threadIdx.x;
    const int lane = tid & 63;
    const int wvid = tid >> 6;            // 0..3 -> n-triple
    const int quad = lane >> 4;
    const int col  = lane & 15;
    const int row0 = blockIdx.x * 32;     // grid 512

    const float* xblk = x + (size_t)row0 * CEMB;
    const bf16* wbase[3];
    #pragma unroll
    for (int j = 0; j < 3; ++j)
        wbase[j] = Wt + (size_t)(wvid * 3 + j) * 32 * 64 * 8 + (size_t)lane * 8;

    // DMA stage: 4 wave-loads (1 KB each) per chunk per wave
    const int sr = lane >> 4;             // row within wave-load 0..3
    const int ss = lane & 15;             // LDS granule slot
    auto stage = [&](int ci, int bufi) {
        #pragma unroll
        for (int h2 = 0; h2 < 2; ++h2)
            #pragma unroll
            for (int j = 0; j < 2; ++j) {
                const int r = wvid * 8 + j * 4 + sr;
                const int c = ss ^ (r & 7);   // global granule (16B = 4 fp32)
                async_ld16(xblk + (size_t)r * CEMB + ci * 128 + h2 * 64 + c * 4,
                           &Xsh[bufi][h2][wvid * 8 + j * 4][0]);
            }
    };

    f32x4 acc[2][3] = {};                 // [row-tile][n-tile]
    bf16x8 bvA[2][3], bvB[2][3];          // half-chunk B-frags (48 VGPR)
    const int c7 = col & 7;

    auto loadBv = [&](int hb, bf16x8 (&tgt)[2][3]) {
        #pragma unroll
        for (int kl = 0; kl < 2; ++kl)
            #pragma unroll
            for (int j = 0; j < 3; ++j)
                tgt[kl][j] = *(const bf16x8*)(wbase[j] + (size_t)(hb + kl) * 512);
    };

    // prologue: stage 0,1; bvA = chunk0 half0
    stage(0, 0); stage(1, 1);
    loadBv(0, bvA);

    #pragma unroll
    for (int ci = 0; ci < 8; ++ci) {      // 8 chunks of 128 k
        barx();                           // readers of chunk ci-1 finished
        loadBv(ci * 4 + 2, bvB);          // current chunk half1
        if (ci + 2 < 8) stage(ci + 2, (ci + 2) % 3);
        wait_vm(ci <= 5 ? 10 : 6);        // own stage(ci)+bvA retired
        barx();                           // all waves' chunk-ci DMA retired
        const int buf = ci % 3;

        // half0: kk = 0,1 with bvA
        #pragma unroll
        for (int kl = 0; kl < 2; ++kl) {
            const int g0 = kl * 8 + quad * 2;
            #pragma unroll
            for (int rt = 0; rt < 2; ++rt) {
                const int r = rt * 16 + col;
                float4 a0 = *(const float4*)&Xsh[buf][0][r][(g0 ^ c7) * 4];
                float4 a1 = *(const float4*)&Xsh[buf][0][r][((g0 + 1) ^ c7) * 4];
                bf16x8 af;
                af[0]=(bf16)a0.x; af[1]=(bf16)a0.y; af[2]=(bf16)a0.z; af[3]=(bf16)a0.w;
                af[4]=(bf16)a1.x; af[5]=(bf16)a1.y; af[6]=(bf16)a1.z; af[7]=(bf16)a1.w;
                #pragma unroll
                for (int j = 0; j < 3; ++j)
                    acc[rt][j] = mfma16(af, bvA[kl][j], acc[rt][j]);
            }
        }
        // prefetch next chunk half0 into bvA (reg WAR keeps order vs reads)
        if (ci + 1 < 8) loadBv((ci + 1) * 4, bvA);
        // half1: kk = 2,3 with bvB
        #pragma unroll
        for (int kl = 0; kl < 2; ++kl) {
            const int g0 = kl * 8 + quad * 2;
            #pragma unroll
            for (int rt = 0; rt < 2; ++rt) {
                const int r = rt * 16 + col;
                float4 a0 = *(const float4*)&Xsh[buf][1][r][(g0 ^ c7) * 4];
                float4 a1 = *(const float4*)&Xsh[buf][1][r][((g0 + 1) ^ c7) * 4];
                bf16x8 af;
                af[0]=(bf16)a0.x; af[1]=(bf16)a0.y; af[2]=(bf16)a0.z; af[3]=(bf16)a0.w;
                af[4]=(bf16)a1.x; af[5]=(bf16)a1.y; af[6]=(bf16)a1.z; af[7]=(bf16)a1.w;
                #pragma unroll
                for (int j = 0; j < 3; ++j)
                    acc[rt][j] = mfma16(af, bvB[kl][j], acc[rt][j]);
            }
        }
    }

    const float* bias[3] = {bq, bk, bv_};
    #pragma unroll
    for (int j = 0; j < 3; ++j) {
        const int jg = wvid * 3 + j;      // global n-tile 0..11
        const int which = jg >> 2;
        const int h = (jg & 3) * 16 + col;
        float bb = bias[which][h];
        if (which == 0) bb *= QSCALE;
        #pragma unroll
        for (int rt = 0; rt < 2; ++rt) {
            if (which < 2) {
                bf16* dst = which == 0 ? qb : kb;
                #pragma unroll
                for (int r = 0; r < 4; ++r) {
                    const int trow = row0 + rt * 16 + quad * 4 + r;
                    dst[(size_t)trow * HEAD + h] = (bf16)(acc[rt][j][r] + bb);
                }
            } else {                      // v -> vT[b][h][t], 4 contig t
                bf16x4 pv;
                #pragma unroll
                for (int r = 0; r < 4; ++r) pv[r] = (bf16)(acc[rt][j][r] + bb);
                const int trow0 = row0 + rt * 16 + quad * 4;
                const int bb_   = trow0 >> 12;
                const int tt    = trow0 & (TLEN - 1);
                *(bf16x4*)(vT + ((size_t)(bb_ * HEAD + h)) * TLEN + tt) = pv;
            }
        }
    }
}

// ---------------------------------------------------------------------------
// Kernel 2: attention v6 (r8's attn, isolated this time).  Compute identical
// to verified v5b; staging ring-3 + counted vmcnt: prefetch distance 2,
// barx + wait_vm(own) replaces the per-chunk __syncthreads vmcnt(0) drain.
// Compute is pure-LDS so the counted stream is unpolluted.
// ---------------------------------------------------------------------------
__global__ __launch_bounds__(256, 2) void attn(
    const bf16* __restrict__ qb, const bf16* __restrict__ kb,
    const bf16* __restrict__ vT,
    bf16* __restrict__ opart, float* __restrict__ lpart,
    float* __restrict__ out, int nsplit, int lg2S)
{
    __shared__ __align__(16) bf16 Ksh[3][64][64];   // 24 KB ring
    __shared__ __align__(16) bf16 Vsh[3][64][64];   // 24 KB ring (V^T: [h][s])

    const int tid  = threadIdx.x;
    const int lane = tid & 63;
    const int wvid = tid >> 6;
    const int l31  = lane & 31;
    const int b5   = lane >> 5;

    int b, sp, qtile;
    {
        const int id = blockIdx.x;
        if (nsplit >= 2) {
            const int cpx = (BATCH << lg2S) >> 3;   // combos per XCD
            const int idx = id >> 3;
            const int combo = (id & 7) * cpx + (idx >> 4);
            qtile = idx & 15;
            b = combo >> lg2S;
            sp = combo & (nsplit - 1);
        } else {
            qtile = id & 15; b = id >> 4; sp = 0;
        }
    }
    const int q0 = qtile * 256 + wvid * 64;
    const size_t rowbase = (size_t)b * TLEN + q0;

    // Q B-frags (32x32x16): lane holds Q[q = l31][h = 16m + 8*b5 .. +7]
    bf16x8 qf[2][4];
    #pragma unroll
    for (int qt = 0; qt < 2; ++qt)
        #pragma unroll
        for (int m = 0; m < 4; ++m)
            qf[qt][m] = *(const bf16x8*)
                (qb + (rowbase + qt * 32 + l31) * HEAD + m * 16 + b5 * 8);

    const bf16* kbB = kb + (size_t)b * TLEN * HEAD;
    const bf16* vTB = vT + (size_t)b * HEAD * TLEN;

    f32x16 o[2][2] = {};                  // [qt][ht]
    float lsum[2] = {0.f, 0.f};

    const int slen = TLEN >> lg2S;
    const int sbeg = sp * slen;
    const int nch  = slen / 64;

    const int r8 = lane >> 3;            // 0..7
    const int s8 = lane & 7;
    auto stage = [&](int s0, int bufi) {
        #pragma unroll
        for (int j = 0; j < 2; ++j) {
            const int r = wvid * 16 + j * 8 + r8;
            const int c = s8 ^ (r & 7);  // global granule (16B = 8 bf16)
            async_ld16(kbB + (size_t)(s0 + r) * HEAD + c * 8,
                       &Ksh[bufi][wvid * 16 + j * 8][0]);
            async_ld16(vTB + (size_t)r * TLEN + s0 + c * 8,
                       &Vsh[bufi][wvid * 16 + j * 8][0]);
        }
    };

    stage(sbeg, 0);
    if (nch > 1) stage(sbeg + 64, 1);
    int buf = 0, sbuf = 2;
    for (int ci = 0; ci < nch; ++ci) {
        barx();                          // readers of chunk ci-1 finished
        if (ci + 2 < nch) stage(sbeg + (ci + 2) * 64, sbuf);
        {                                // own stage(ci) retired
            int n = nch - 1 - ci; if (n > 2) n = 2;
            wait_vm(4 * n);
        }
        barx();                          // all waves' chunk-ci DMA retired

        #pragma unroll
        for (int kt = 0; kt < 2; ++kt) {
            const int kr = kt * 32 + l31;
            const int k7 = kr & 7;
            bf16x8 kf[4];
            #pragma unroll
            for (int m = 0; m < 4; ++m)
                kf[m] = *(const bf16x8*)&Ksh[buf][kr][((2 * m + b5) ^ k7) * 8];

            bf16x8 pb[2][2];             // [qt][kc] PV B-frags
            #pragma unroll
            for (int qt = 0; qt < 2; ++qt) {
                f32x16 st = {};
                #pragma unroll
                for (int m = 0; m < 4; ++m)
                    st = mfma32(kf[m], qf[qt][m], st);
                // D: q = l31, key = kt*32 + (r&3) + 8*(r>>2) + 4*b5
                float e[16];
                #pragma unroll
                for (int r = 0; r < 16; ++r)
                    e[r] = __builtin_amdgcn_exp2f(st[r]);
                float t0 = (e[0] + e[1]) + (e[2] + e[3]);
                float t1 = (e[4] + e[5]) + (e[6] + e[7]);
                float t2 = (e[8] + e[9]) + (e[10] + e[11]);
                float t3 = (e[12] + e[13]) + (e[14] + e[15]);
                lsum[qt] += (t0 + t1) + (t2 + t3);
                unsigned w[8];
                #pragma unroll
                for (int s = 0; s < 8; ++s)
                    w[s] = cvt_pk_bf16(e[2 * s], e[2 * s + 1]);
                #pragma unroll
                for (int kc = 0; kc < 2; ++kc) {
                    auto s02 = __builtin_amdgcn_permlane32_swap(
                        w[4 * kc + 0], w[4 * kc + 2], false, false);
                    auto s13 = __builtin_amdgcn_permlane32_swap(
                        w[4 * kc + 1], w[4 * kc + 3], false, false);
                    u32x4 pw = { (unsigned)s02[0], (unsigned)s13[0],
                                 (unsigned)s02[1], (unsigned)s13[1] };
                    pb[qt][kc] = __builtin_bit_cast(bf16x8, pw);
                }
            }
            #pragma unroll
            for (int ht = 0; ht < 2; ++ht) {
                const int vr = ht * 32 + l31;
                const int v7 = vr & 7;
                #pragma unroll
                for (int kc = 0; kc < 2; ++kc) {
                    bf16x8 vf = *(const bf16x8*)
                        &Vsh[buf][vr][((2 * (2 * kt + kc) + b5) ^ v7) * 8];
                    #pragma unroll
                    for (int qt = 0; qt < 2; ++qt)
                        o[qt][ht] = mfma32(vf, pb[qt][kc], o[qt][ht]);
                }
            }
        }
        buf  = (buf  == 2) ? 0 : buf  + 1;
        sbuf = (sbuf == 2) ? 0 : sbuf + 1;
    }

    #pragma unroll
    for (int qt = 0; qt < 2; ++qt)
        lsum[qt] += __shfl_xor(lsum[qt], 32, 64);

    #pragma unroll
    for (int qt = 0; qt < 2; ++qt) {
        const size_t grow = rowbase + qt * 32 + l31;
        if (nsplit == 1) {
            const float inv = 1.f / lsum[qt];
            float* ob = out + grow * HEAD;
            #pragma unroll
            for (int ht = 0; ht < 2; ++ht)
                #pragma unroll
                for (int g = 0; g < 4; ++g) {
                    f32x4 r = { o[qt][ht][4*g+0] * inv, o[qt][ht][4*g+1] * inv,
                                o[qt][ht][4*g+2] * inv, o[qt][ht][4*g+3] * inv };
                    *(f32x4*)(ob + ht * 32 + g * 8 + b5 * 4) = r;
                }
        } else if (sp == 0) {
            float* ob = out + grow * HEAD;
            #pragma unroll
            for (int ht = 0; ht < 2; ++ht)
                #pragma unroll
                for (int g = 0; g < 4; ++g) {
                    f32x4 r = { o[qt][ht][4*g+0], o[qt][ht][4*g+1],
                                o[qt][ht][4*g+2], o[qt][ht][4*g+3] };
                    *(f32x4*)(ob + ht * 32 + g * 8 + b5 * 4) = r;
                }
            if (lane < 32) lpart[grow] = lsum[qt];
        } else {
            bf16* ob = opart + ((size_t)(sp - 1) * NROWS + grow) * HEAD;
            #pragma unroll
            for (int ht = 0; ht < 2; ++ht)
                #pragma unroll
                for (int g = 0; g < 4; ++g) {
                    bf16x4 r = { (bf16)o[qt][ht][4*g+0], (bf16)o[qt][ht][4*g+1],
                                 (bf16)o[qt][ht][4*g+2], (bf16)o[qt][ht][4*g+3] };
                    *(bf16x4*)(ob + ht * 32 + g * 8 + b5 * 4) = r;
                }
            if (lane < 32) lpart[(size_t)sp * NROWS + grow] = lsum[qt];
        }
    }
}

// ---------------------------------------------------------------------------
// Kernel 3: combine.  Fixed-max partials share one scale -> plain sums.
// ---------------------------------------------------------------------------
__global__ __launch_bounds__(256) void combine(
    const bf16* __restrict__ opart, const float* __restrict__ lpart,
    float* __restrict__ out, int nsplit)
{
    const int gid = blockIdx.x * 256 + threadIdx.x;
    const int row = gid >> 4;
    const int h4  = (gid & 15) * 4;

    float L = 0.f;
    for (int s = 0; s < nsplit; ++s) L += lpart[(size_t)s * NROWS + row];
    f32x4 O = *(const f32x4*)(out + (size_t)row * HEAD + h4);
    for (int s = 1; s < nsplit; ++s) {
        bf16x4 v = *(const bf16x4*)(opart + ((size_t)(s - 1) * NROWS + row) * HEAD + h4);
        O[0] += (float)v[0]; O[1] += (float)v[1];
        O[2] += (float)v[2]; O[3] += (float)v[3];
    }
    f32x4 r = O * (1.f / L);
    *(f32x4*)(out + (size_t)row * HEAD + h4) = r;
}

// ---------------------------------------------------------------------------
extern "C" void kernel_launch(void* const* d_in, const int* in_sizes, int n_in,
                              void* d_out, int out_size, void* d_ws, size_t ws_size,
                              hipStream_t stream) {
    const float* x  = (const float*)d_in[0];
    const float* Wq = (const float*)d_in[1];
    const float* bq = (const float*)d_in[2];
    const float* Wk = (const float*)d_in[3];
    const float* bk = (const float*)d_in[4];
    const float* Wv = (const float*)d_in[5];
    const float* bv = (const float*)d_in[6];
    float* out = (float*)d_out;

    const size_t n_tok = (size_t)NROWS * HEAD;          // 1,048,576
    char* ws = (char*)d_ws;
    bf16* qb = (bf16*)ws;
    bf16* kb = qb + n_tok;
    bf16* vT = kb + n_tok;
    bf16* Wt = vT + n_tok;
    const size_t base = 3 * n_tok * sizeof(bf16) + 192 * CEMB * sizeof(bf16);

    auto need = [&](int S) {
        return base + (size_t)(S - 1) * n_tok * sizeof(bf16)
                    + (size_t)S * NROWS * sizeof(float);
    };
    int S = 1, lg2S = 0;
    if      (ws_size >= need(8)) { S = 8; lg2S = 3; }
    else if (ws_size >= need(4)) { S = 4; lg2S = 2; }
    else if (ws_size >= need(2)) { S = 2; lg2S = 1; }
    bf16*  opart = Wt + 192 * CEMB;
    float* lpart = (float*)(opart + (size_t)(S - 1) * n_tok);

    pack_w<<<dim3(24), dim3(256), 0, stream>>>(Wq, Wk, Wv, Wt);
    qkv<<<dim3(512), dim3(256), 0, stream>>>(x, Wt, bq, bk, bv, qb, kb, vT);
    attn<<<dim3(16 * BATCH * S), dim3(256), 0, stream>>>(
        qb, kb, vT, opart, lpart, out, S, lg2S);
    if (S > 1)
        combine<<<dim3((NROWS * 16) / 256), dim3(256), 0, stream>>>(
            opart, lpart, out, S);
}